// Round 6
// baseline (87.461 us; speedup 1.0000x reference)
//
#include <hip/hip_runtime.h>
#include <hip/hip_fp16.h>
#include <math.h>

#define B_N   2
#define A_N   180
#define HR_N  512
#define H_OUT 512
#define W_OUT 512
#define PAD   51               // int(0.1 * 512)
#define HP    614              // H_OUT + 2*PAD
#define WP    614
#define GUARD 80               // zero guard each side
#define HPP   (HP + 2*GUARD)   // 774
#define NPIX  (H_OUT * W_OUT)

#define TW    16               // tile width (pixels)
#define TH    8                // tile height -> 128 px; 256 thr = 4 angle-quarters x 64
#define QA    45               // angles per quarter
#define CH_Q  15               // angles per half2-accumulation group (numerics-preserving)
#define NCH   3                // groups (QA / CH_Q)
#define WIN   20               // window entries per angle per tile (span <= 18.6)
#define NWIN  (A_N * WIN)      // 3600 entries staged ONCE (28.8 KB)

// Workspace:
//   pk2[A_N][HPP] uint2: {half2(b0[y],b1[y]), half2(b0[y+1],b1[y+1])}, zero-guarded
//   tg[A_N] float2: {cos, sin}

__device__ __forceinline__ float col_val(const float* __restrict__ sino,
                                         int b, int a, int yy) {
    if (yy < 0 || yy >= HP) return 0.0f;
    float src = ((float)yy + 0.5f) * ((float)HR_N / (float)HP) - 0.5f;
    src = fminf(fmaxf(src, 0.0f), (float)(HR_N - 1));
    int i0 = (int)floorf(src);
    int i1 = min(i0 + 1, HR_N - 1);
    float wH = src - (float)i0;
    const float* srow = sino + ((size_t)b * A_N + a) * HR_N;
    return srow[i0] * (1.0f - wH) + srow[i1] * wH;
}

__global__ void prep_kernel(const float* __restrict__ sino,
                            const float* __restrict__ angles,
                            uint2* __restrict__ pk2,
                            float2* __restrict__ tg) {
    int idx = blockIdx.x * blockDim.x + threadIdx.x;
    if (idx < A_N) {
        float th = -angles[idx] * (float)(M_PI / 180.0);
        tg[idx] = make_float2(cosf(th), sinf(th));
    }
    const int total = A_N * HPP;
    if (idx < total) {
        int y = idx % HPP;
        int a = idx / HPP;
        int yy = y - GUARD;
        float v00 = col_val(sino, 0, a, yy);
        float v10 = col_val(sino, 1, a, yy);
        float v01 = col_val(sino, 0, a, yy + 1);
        float v11 = col_val(sino, 1, a, yy + 1);
        __half2 lo = __floats2half2_rn(v00, v10);
        __half2 hi = __floats2half2_rn(v01, v11);
        uint2 u;
        u.x = *(unsigned int*)&lo;
        u.y = *(unsigned int*)&hi;
        pk2[idx] = u;
    }
}

// Single-stage structure: ALL 180 angle-windows staged once (28.8 KB), then a
// barrier-free 45-angle compute loop per wave. Arithmetic order identical to
// the 3-chunk version (15-angle half2 accumulator groups preserved).
template <bool INTERIOR>
__device__ __forceinline__ void bp_compute(const float4* __restrict__ s_cs,
                                           const uint2* __restrict__ s_win,
                                           int q, float X, float Y,
                                           float& a00, float& a01, float& a10, float& a11) {
    const int abase0 = q * QA;
    for (int ch = 0; ch < NCH; ++ch) {
        const int abase = abase0 + ch * CH_Q;
        if (INTERIOR) {
            __half2 h0 = __float2half2_rn(0.0f);
            __half2 h1 = __float2half2_rn(0.0f);
#pragma unroll
            for (int la = 0; la < CH_Q; ++la) {
                int a = abase + la;
                float4 cs = s_cs[a];                // broadcast ds_read_b128 {c,s,Kf}
                float c = cs.x, s = cs.y;
                float f0 = fmaf(s, X, fmaf(c, Y, cs.z));   // == s*X + c*Y + (315.5 - floor(iyc))
                float f1 = f0 + s;
                int   li0 = (int)f0;  float wy0 = __builtin_amdgcn_fractf(f0); // f0>0: fract==trunc-sub
                int   li1 = (int)f1;  float wy1 = f1 - (float)li1;             // f1 may dip <0: keep trunc
                uint2 cv0 = s_win[a * WIN + li0];   // ds_read_b64
                uint2 cv1 = s_win[a * WIN + li1];
                __half2 lo0 = *(__half2*)&cv0.x, hi0 = *(__half2*)&cv0.y;
                __half2 lo1 = *(__half2*)&cv1.x, hi1 = *(__half2*)&cv1.y;
                h0 = __hadd2(h0, __hfma2(__float2half2_rn(wy0), __hsub2(hi0, lo0), lo0));
                h1 = __hadd2(h1, __hfma2(__float2half2_rn(wy1), __hsub2(hi1, lo1), lo1));
            }
            a00 += __low2float(h0);  a01 += __high2float(h0);
            a10 += __low2float(h1);  a11 += __high2float(h1);
        } else {
#pragma unroll
            for (int la = 0; la < CH_Q; ++la) {
                int a = abase + la;
                float4 cs = s_cs[a];
                float c = cs.x, s = cs.y;
                float f0 = fmaf(s, X, fmaf(c, Y, cs.z));
                float f1 = f0 + s;
                int   li0 = (int)f0;  float wy0 = __builtin_amdgcn_fractf(f0);
                int   li1 = (int)f1;  float wy1 = f1 - (float)li1;
                uint2 cv0 = s_win[a * WIN + li0];
                uint2 cv1 = s_win[a * WIN + li1];
                __half2 lo0 = *(__half2*)&cv0.x, hi0 = *(__half2*)&cv0.y;
                __half2 lo1 = *(__half2*)&cv1.x, hi1 = *(__half2*)&cv1.y;
                __half2 r0 = __hfma2(__float2half2_rn(wy0), __hsub2(hi0, lo0), lo0);
                __half2 r1 = __hfma2(__float2half2_rn(wy1), __hsub2(hi1, lo1), lo1);
                float ix0 = fmaf(c, X, fmaf(-s, Y, 306.5f));
                float ix1 = ix0 + c;
                float xf0 = fminf(fmaxf(ix0 + 1.0f, 0.0f), 1.0f)
                          * fminf(fmaxf((float)WP - ix0, 0.0f), 1.0f);
                float xf1 = fminf(fmaxf(ix1 + 1.0f, 0.0f), 1.0f)
                          * fminf(fmaxf((float)WP - ix1, 0.0f), 1.0f);
                a00 = fmaf(xf0, __low2float(r0),  a00);
                a01 = fmaf(xf0, __high2float(r0), a01);
                a10 = fmaf(xf1, __low2float(r1),  a10);
                a11 = fmaf(xf1, __high2float(r1), a11);
            }
        }
    }
}

__global__ __launch_bounds__(256, 4) void bp_kernel(const uint2* __restrict__ pk2,
                                                    const float2* __restrict__ tgv,
                                                    float* __restrict__ out) {
    __shared__ float4   s_cs[A_N];             // {cos, sin, Kf, -}          2.88 KB
    __shared__ unsigned s_off[A_N];            // window start in pk2        0.72 KB
    __shared__ uint2    s_win[NWIN];           // ALL angle-windows          28.8 KB
    __shared__ float    s_red[3][256];         // quarter reduction          3.07 KB

    int t  = threadIdx.x;
    int tx = blockIdx.x, ty = blockIdx.y;
    float Xc = (float)(tx * TW) - 248.0f;      // tile-center X (= +7.5 - 255.5)
    float Yc = (float)(ty * TH) - 252.0f;      // tile-center Y (= +3.5 - 255.5)

    if (t < A_N) {
        float2 cs = tgv[t];
        float iyc = fmaf(cs.y, Xc, fmaf(cs.x, Yc, 306.5f));
        int base = (int)floorf(iyc) - 9;       // window covers [base, base+19]
        s_cs[t]  = make_float4(cs.x, cs.y, 306.5f - (float)base, 0.0f); // Kf = 315.5 - floor(iyc)
        s_off[t] = (unsigned)(t * HPP + GUARD + base);
    }
    __syncthreads();

    // Stage ALL 180 windows in one pass: 15 independent scattered loads/thread,
    // no intervening barriers -> fully pipelined vmem.
    for (int e = t; e < NWIN; e += 256) {
        int a = e / WIN;
        int j = e - a * WIN;
        s_win[e] = pk2[s_off[a] + (unsigned)j];
    }
    __syncthreads();

    int q  = t >> 6;                           // quarter = wave id (angles q*45..q*45+44)
    int tt = t & 63;
    int lx = (tt & 7) << 1;                    // 0,2,...,14 (2 px per thread in x)
    int ly = tt >> 3;                          // 0..7
    float X = (float)(tx * TW + lx) - 255.5f;
    float Y = (float)(ty * TH + ly) - 255.5f;

    float a00 = 0.0f, a01 = 0.0f, a10 = 0.0f, a11 = 0.0f;

    // Interior tiles: ix in [0,613] for every pixel & angle -> xfac == 1
    bool interior = (Xc * Xc + Yc * Yc) <= 87500.0f;
    if (interior)
        bp_compute<true >(s_cs, s_win, q, X, Y, a00, a01, a10, a11);
    else
        bp_compute<false>(s_cs, s_win, q, X, Y, a00, a01, a10, a11);

    // 4-quarter reduction in LDS (no atomics, no global memset)
    int pix = ly * TW + lx;                    // 0..126 even
    if (q != 0) {
        s_red[q - 1][pix]           = a00;
        s_red[q - 1][pix + 1]       = a10;
        s_red[q - 1][128 + pix]     = a01;
        s_red[q - 1][128 + pix + 1] = a11;
    }
    __syncthreads();
    if (q == 0) {
        const float inv = 1.0f / (180.0f + 1e-6f);
        float2 v0, v1;
        v0.x = (a00 + s_red[0][pix]       + s_red[1][pix]       + s_red[2][pix])       * inv;
        v0.y = (a10 + s_red[0][pix+1]     + s_red[1][pix+1]     + s_red[2][pix+1])     * inv;
        v1.x = (a01 + s_red[0][128+pix]   + s_red[1][128+pix]   + s_red[2][128+pix])   * inv;
        v1.y = (a11 + s_red[0][128+pix+1] + s_red[1][128+pix+1] + s_red[2][128+pix+1]) * inv;
        int idx = (ty * TH + ly) * W_OUT + (tx * TW + lx);
        *(float2*)(out + idx)        = v0;     // 8B-aligned (idx even)
        *(float2*)(out + NPIX + idx) = v1;
    }
}

extern "C" void kernel_launch(void* const* d_in, const int* in_sizes, int n_in,
                              void* d_out, int out_size, void* d_ws, size_t ws_size,
                              hipStream_t stream) {
    const float* sino   = (const float*)d_in[0];
    const float* angles = (const float*)d_in[1];
    char*   ws  = (char*)d_ws;
    uint2*  pk2 = (uint2*)ws;                              // A_N * HPP * 8 B
    float2* tg  = (float2*)(ws + (size_t)A_N * HPP * sizeof(uint2));

    const int total = A_N * HPP;
    prep_kernel<<<(total + 255) / 256, 256, 0, stream>>>(sino, angles, pk2, tg);

    dim3 grid(W_OUT / TW, H_OUT / TH);                     // 32 x 64 = 2048 blocks
    bp_kernel<<<grid, 256, 0, stream>>>(pk2, tg, (float*)d_out);
}

// Round 7
// 82.250 us; speedup vs baseline: 1.0634x; 1.0634x over previous
//
#include <hip/hip_runtime.h>
#include <hip/hip_fp16.h>
#include <math.h>

#define B_N   2
#define A_N   180
#define HR_N  512
#define H_OUT 512
#define W_OUT 512
#define PAD   51               // int(0.1 * 512)
#define HP    614              // H_OUT + 2*PAD
#define WP    614
#define GUARD 80               // zero guard each side
#define HPP   (HP + 2*GUARD)   // 774
#define NPIX  (H_OUT * W_OUT)

#define TW    16               // tile width (pixels)
#define TH    16               // tile height -> 256 px; 4 px per thread (2x * 2y)
#define QA    45               // angles per quarter (4 quarters = 4 waves)
#define CH_Q  15               // angles per quarter per LDS chunk
#define NCH   3                // chunks (QA / CH_Q)
#define WIN   24               // window entries per angle (span <= 2*10.61, base=floor-11)
#define CHUNK_E (4 * CH_Q * WIN)   // 1440 entries per chunk (11.52 KB)

// Workspace:
//   pk2[A_N][HPP] uint2: {half2(b0[y],b1[y]), half2(b0[y+1],b1[y+1])}, zero-guarded
//   tg[A_N] float2: {cos, sin}

__device__ __forceinline__ float col_val(const float* __restrict__ sino,
                                         int b, int a, int yy) {
    if (yy < 0 || yy >= HP) return 0.0f;
    float src = ((float)yy + 0.5f) * ((float)HR_N / (float)HP) - 0.5f;
    src = fminf(fmaxf(src, 0.0f), (float)(HR_N - 1));
    int i0 = (int)floorf(src);
    int i1 = min(i0 + 1, HR_N - 1);
    float wH = src - (float)i0;
    const float* srow = sino + ((size_t)b * A_N + a) * HR_N;
    return srow[i0] * (1.0f - wH) + srow[i1] * wH;
}

__global__ void prep_kernel(const float* __restrict__ sino,
                            const float* __restrict__ angles,
                            uint2* __restrict__ pk2,
                            float2* __restrict__ tg) {
    int idx = blockIdx.x * blockDim.x + threadIdx.x;
    if (idx < A_N) {
        float th = -angles[idx] * (float)(M_PI / 180.0);
        tg[idx] = make_float2(cosf(th), sinf(th));
    }
    const int total = A_N * HPP;
    if (idx < total) {
        int y = idx % HPP;
        int a = idx / HPP;
        int yy = y - GUARD;
        float v00 = col_val(sino, 0, a, yy);
        float v10 = col_val(sino, 1, a, yy);
        float v01 = col_val(sino, 0, a, yy + 1);
        float v11 = col_val(sino, 1, a, yy + 1);
        __half2 lo = __floats2half2_rn(v00, v10);
        __half2 hi = __floats2half2_rn(v01, v11);
        uint2 u;
        u.x = *(unsigned int*)&lo;
        u.y = *(unsigned int*)&hi;
        pk2[idx] = u;
    }
}

__device__ __forceinline__ __half2 interp(uint2 cv, float w) {
    __half2 lo = *(__half2*)&cv.x, hi = *(__half2*)&cv.y;
    return __hfma2(__float2half2_rn(w), __hsub2(hi, lo), lo);
}

// 4 px/thread: x-pair (X, X+1), y-pair (Y, Y+8). f00 exact; neighbors
// incremental (+s, +8c) — bounded in [0.39, 22.61] by tile geometry, so
// fract/trunc are safe and all window reads in [0, 23].
// p** = y-row0 accumulators, q** = y-row1; *0*=px x0, *1*=px x1; last=batch.
template <bool INTERIOR>
__device__ __forceinline__ void bp_body(const uint2* __restrict__ pk2,
                                        const float4* __restrict__ s_cs,
                                        uint2* __restrict__ s_win,
                                        int t, int q, float X, float Y,
                                        float& p00, float& p01, float& p10, float& p11,
                                        float& q00, float& q01, float& q10, float& q11) {
    for (int ch = 0; ch < NCH; ++ch) {
        // Stage CH_Q angle-windows for ALL 4 quarters into LDS (1440 uint2)
        for (int e = t; e < CHUNK_E; e += 256) {
            int wid = e / WIN;
            int j   = e - wid * WIN;
            int qq  = wid / CH_Q;
            int la  = wid - qq * CH_Q;
            int a   = qq * QA + ch * CH_Q + la;
            s_win[e] = pk2[__float_as_uint(s_cs[a].w) + (unsigned)j];
        }
        __syncthreads();

        const int abase = q * QA + ch * CH_Q;     // wave-uniform
        const int wbase = q * (CH_Q * WIN);
        if (INTERIOR) {
            __half2 h00 = __float2half2_rn(0.0f);
            __half2 h01 = __float2half2_rn(0.0f);
            __half2 h10 = __float2half2_rn(0.0f);
            __half2 h11 = __float2half2_rn(0.0f);
#pragma unroll
            for (int la = 0; la < CH_Q; ++la) {
                float4 cs = s_cs[abase + la];       // broadcast ds_read_b128 {c,s,Kf,off}
                float c = cs.x, s = cs.y;
                float f00 = fmaf(s, X, fmaf(c, Y, cs.z));  // == iy - base, in [0.39,22.61]
                float f01 = f00 + s;
                float f10 = f00 + 8.0f * c;
                float f11 = f10 + s;
                int i00 = (int)f00;  float w00 = __builtin_amdgcn_fractf(f00);
                int i01 = (int)f01;  float w01 = __builtin_amdgcn_fractf(f01);
                int i10 = (int)f10;  float w10 = __builtin_amdgcn_fractf(f10);
                int i11 = (int)f11;  float w11 = __builtin_amdgcn_fractf(f11);
                const int wb = wbase + la * WIN;
                uint2 v00 = s_win[wb + i00];        // 4 independent ds_read_b64 chains
                uint2 v01 = s_win[wb + i01];
                uint2 v10 = s_win[wb + i10];
                uint2 v11 = s_win[wb + i11];
                h00 = __hadd2(h00, interp(v00, w00));
                h01 = __hadd2(h01, interp(v01, w01));
                h10 = __hadd2(h10, interp(v10, w10));
                h11 = __hadd2(h11, interp(v11, w11));
            }
            p00 += __low2float(h00);  p01 += __high2float(h00);
            p10 += __low2float(h01);  p11 += __high2float(h01);
            q00 += __low2float(h10);  q01 += __high2float(h10);
            q10 += __low2float(h11);  q11 += __high2float(h11);
        } else {
#pragma unroll
            for (int la = 0; la < CH_Q; ++la) {
                float4 cs = s_cs[abase + la];
                float c = cs.x, s = cs.y;
                float f00 = fmaf(s, X, fmaf(c, Y, cs.z));
                float f01 = f00 + s;
                float f10 = f00 + 8.0f * c;
                float f11 = f10 + s;
                int i00 = (int)f00;  float w00 = __builtin_amdgcn_fractf(f00);
                int i01 = (int)f01;  float w01 = __builtin_amdgcn_fractf(f01);
                int i10 = (int)f10;  float w10 = __builtin_amdgcn_fractf(f10);
                int i11 = (int)f11;  float w11 = __builtin_amdgcn_fractf(f11);
                const int wb = wbase + la * WIN;
                __half2 r00 = interp(s_win[wb + i00], w00);
                __half2 r01 = interp(s_win[wb + i01], w01);
                __half2 r10 = interp(s_win[wb + i10], w10);
                __half2 r11 = interp(s_win[wb + i11], w11);
                float ix00 = fmaf(c, X, fmaf(-s, Y, 306.5f));
                float ix01 = ix00 + c;
                float ix10 = ix00 - 8.0f * s;
                float ix11 = ix10 + c;
                float xf00 = fminf(fmaxf(ix00 + 1.0f, 0.0f), 1.0f)
                           * fminf(fmaxf((float)WP - ix00, 0.0f), 1.0f);
                float xf01 = fminf(fmaxf(ix01 + 1.0f, 0.0f), 1.0f)
                           * fminf(fmaxf((float)WP - ix01, 0.0f), 1.0f);
                float xf10 = fminf(fmaxf(ix10 + 1.0f, 0.0f), 1.0f)
                           * fminf(fmaxf((float)WP - ix10, 0.0f), 1.0f);
                float xf11 = fminf(fmaxf(ix11 + 1.0f, 0.0f), 1.0f)
                           * fminf(fmaxf((float)WP - ix11, 0.0f), 1.0f);
                p00 = fmaf(xf00, __low2float(r00),  p00);
                p01 = fmaf(xf00, __high2float(r00), p01);
                p10 = fmaf(xf01, __low2float(r01),  p10);
                p11 = fmaf(xf01, __high2float(r01), p11);
                q00 = fmaf(xf10, __low2float(r10),  q00);
                q01 = fmaf(xf10, __high2float(r10), q01);
                q10 = fmaf(xf11, __low2float(r11),  q10);
                q11 = fmaf(xf11, __high2float(r11), q11);
            }
        }
        __syncthreads();
    }
}

__global__ __launch_bounds__(256, 4) void bp_kernel(const uint2* __restrict__ pk2,
                                                    const float2* __restrict__ tgv,
                                                    float* __restrict__ out) {
    __shared__ float4 s_cs[A_N];               // {cos, sin, Kf, bitcast(off)}  2.88 KB
    __shared__ uint2  s_win[CHUNK_E];          // 11.52 KB
    __shared__ float  s_red[3 * 64 * 9];       // 8 vals/thread, stride 9 (bank-clean) 6.75 KB

    int t  = threadIdx.x;
    int tx = blockIdx.x, ty = blockIdx.y;
    float Xc = (float)(tx * TW) - 248.0f;      // tile-center X (= +7.5 - 255.5)
    float Yc = (float)(ty * TH) - 248.0f;      // tile-center Y (= +7.5 - 255.5)

    if (t < A_N) {
        float2 cs = tgv[t];
        float iyc = fmaf(cs.y, Xc, fmaf(cs.x, Yc, 306.5f));
        int base = (int)floorf(iyc) - 11;      // window covers [base, base+23]
        s_cs[t] = make_float4(cs.x, cs.y, 306.5f - (float)base,
                              __uint_as_float((unsigned)(t * HPP + GUARD + base)));
    }

    int q  = t >> 6;                           // quarter = wave id (angles q*45..q*45+44)
    int tt = t & 63;
    int lx = (tt & 7) << 1;                    // 0,2,...,14 (2 px per thread in x)
    int ly = tt >> 3;                          // 0..7 (rows ly and ly+8)
    float X = (float)(tx * TW + lx) - 255.5f;
    float Y = (float)(ty * TH + ly) - 255.5f;

    float p00 = 0.0f, p01 = 0.0f, p10 = 0.0f, p11 = 0.0f;
    float q00 = 0.0f, q01 = 0.0f, q10 = 0.0f, q11 = 0.0f;
    __syncthreads();

    // Interior: ix in [0,613] for all px/angles. Needs r <= 306.5-10.61=295.9
    // (r^2 <= 87548); 87500 is just inside.
    bool interior = (Xc * Xc + Yc * Yc) <= 87500.0f;
    if (interior)
        bp_body<true >(pk2, s_cs, s_win, t, q, X, Y, p00, p01, p10, p11, q00, q01, q10, q11);
    else
        bp_body<false>(pk2, s_cs, s_win, t, q, X, Y, p00, p01, p10, p11, q00, q01, q10, q11);

    // 4-quarter reduction in LDS (8 floats/thread, stride 9 to avoid bank conflicts)
    if (q != 0) {
        float* r = &s_red[((q - 1) * 64 + tt) * 9];
        r[0] = p00; r[1] = p01; r[2] = p10; r[3] = p11;
        r[4] = q00; r[5] = q01; r[6] = q10; r[7] = q11;
    }
    __syncthreads();
    if (q == 0) {
        const float inv = 1.0f / (180.0f + 1e-6f);
        const float* r0 = &s_red[tt * 9];
        const float* r1 = &s_red[(64 + tt) * 9];
        const float* r2 = &s_red[(128 + tt) * 9];
        int col  = tx * TW + lx;
        int idx0 = (ty * TH + ly) * W_OUT + col;       // row ly
        int idx1 = idx0 + 8 * W_OUT;                   // row ly+8
        float2 o;
        o.x = (p00 + r0[0] + r1[0] + r2[0]) * inv;     // y0 x0 b0
        o.y = (p10 + r0[2] + r1[2] + r2[2]) * inv;     // y0 x1 b0
        *(float2*)(out + idx0) = o;
        o.x = (p01 + r0[1] + r1[1] + r2[1]) * inv;     // y0 x0 b1
        o.y = (p11 + r0[3] + r1[3] + r2[3]) * inv;     // y0 x1 b1
        *(float2*)(out + NPIX + idx0) = o;
        o.x = (q00 + r0[4] + r1[4] + r2[4]) * inv;     // y1 x0 b0
        o.y = (q10 + r0[6] + r1[6] + r2[6]) * inv;     // y1 x1 b0
        *(float2*)(out + idx1) = o;
        o.x = (q01 + r0[5] + r1[5] + r2[5]) * inv;     // y1 x0 b1
        o.y = (q11 + r0[7] + r1[7] + r2[7]) * inv;     // y1 x1 b1
        *(float2*)(out + NPIX + idx1) = o;
    }
}

extern "C" void kernel_launch(void* const* d_in, const int* in_sizes, int n_in,
                              void* d_out, int out_size, void* d_ws, size_t ws_size,
                              hipStream_t stream) {
    const float* sino   = (const float*)d_in[0];
    const float* angles = (const float*)d_in[1];
    char*   ws  = (char*)d_ws;
    uint2*  pk2 = (uint2*)ws;                              // A_N * HPP * 8 B
    float2* tg  = (float2*)(ws + (size_t)A_N * HPP * sizeof(uint2));

    const int total = A_N * HPP;
    prep_kernel<<<(total + 255) / 256, 256, 0, stream>>>(sino, angles, pk2, tg);

    dim3 grid(W_OUT / TW, H_OUT / TH);                     // 32 x 32 = 1024 blocks
    bp_kernel<<<grid, 256, 0, stream>>>(pk2, tg, (float*)d_out);
}